// Round 10
// baseline (104.285 us; speedup 1.0000x reference)
//
#include <hip/hip_runtime.h>

// DIAGNOSTIC ROUND: phase-split probes with z-replication so each phase's
// dispatch exceeds the harness fillBuffer bar (~40us) and becomes visible in
// rocprof top-5 with full counters. Final fused kernel (r9 verbatim) rewrites
// d_out so correctness never depends on the probes.
//
//   dmh_p1 (z=4): r9 phase 1 exactly (float4 feature loads + per-px MLP),
//                 mask rows -> ws[inst][slice][10][128]. z-replicas benign.
//   dmh_p2 (z=10): ws mask -> LDS -> r9 phase 2 (bilinear+sigmoid).
//                 z==0 writes d_out, z>0 write ws dump (identical values).
//   dmh_kernel:   r9 fused kernel, rewrites d_out with correct values.

#define HH 192
#define WW 256
#define IH 96
#define IW 128
#define HW (HH * WW)
#define NSL 12
#define MROWS 10
#define WS_DUMP_OFF (32u * 1024u * 1024u)

__device__ __forceinline__ float mlp_px(
    const float* __restrict__ p, const float* f, float relx, float rely)
{
    float a[8];
    #pragma unroll
    for (int k = 0; k < 8; ++k) {
        float acc = p[152 + k];
        acc = fmaf(p[k * 10 + 0], relx, acc);
        acc = fmaf(p[k * 10 + 1], rely, acc);
        #pragma unroll
        for (int c = 0; c < 8; ++c)
            acc = fmaf(p[k * 10 + 2 + c], f[c], acc);
        a[k] = fmaxf(acc, 0.0f);
    }
    float b[8];
    #pragma unroll
    for (int k = 0; k < 8; ++k) {
        float acc = p[160 + k];
        #pragma unroll
        for (int c = 0; c < 8; ++c)
            acc = fmaf(p[80 + k * 8 + c], a[c], acc);
        b[k] = fmaxf(acc, 0.0f);
    }
    float acc = p[168];
    #pragma unroll
    for (int c = 0; c < 8; ++c)
        acc = fmaf(p[144 + c], b[c], acc);
    return acc;
}

__device__ __forceinline__ void inst_setup(
    const float* __restrict__ locs, const int* __restrict__ im_inds,
    const int* __restrict__ fpn, int inst,
    float& ix, float& iy, float& inv_soi, int& im, int& gx, int& gy)
{
    ix = locs[2 * inst + 0];
    iy = locs[2 * inst + 1];
    inv_soi = 1.0f / (float)(64 << fpn[inst]);
    im = im_inds[inst];
    const float nlx = ix * 0.125f;
    const float nly = iy * 0.125f;
    gx = (int)floorf(fminf(fmaxf(nlx, 0.0f), (float)(WW - 1)) / (float)(WW / 2));
    gy = (int)floorf(fminf(fmaxf(nly, 0.0f), (float)(HH - 1)) / (float)(HH / 2));
}

// ---------------- Probe 1: phase 1 only (loads + MLP -> ws mask) -----------
__global__ __launch_bounds__(256, 6) void dmh_p1(
    const float* __restrict__ mf, const float* __restrict__ params,
    const float* __restrict__ locs, const int* __restrict__ im_inds,
    const int* __restrict__ fpn, const int* __restrict__ stride_p,
    float* __restrict__ wsmask)
{
    const int bx   = blockIdx.x;
    const int inst = bx / NSL;
    const int j    = bx - inst * NSL;
    const int tid  = threadIdx.x;

    const int s  = stride_p[0];
    const int sh = s >> 1;
    float ix, iy, inv_soi; int im, gx, gy;
    inst_setup(locs, im_inds, fpn, inst, ix, iy, inv_soi, im, gx, gy);
    const float* __restrict__ p = params + inst * 169;

    const int orow0 = j * 16;
    const int ms    = (orow0 * 95) / 191;

    const int col4 = (tid & 31) * 4;
    const int rs   = tid >> 5;
    const float relx0 = (ix - (float)((gx * IW + col4) * s + sh)) * inv_soi;
    const float dstep = (float)s * inv_soi;
    const float* fcol = mf + (size_t)(im * 8) * HW + gx * IW + col4;

    #pragma unroll
    for (int pass = 0; pass < 2; ++pass) {
        const int r = rs + pass * 8;
        if (r < MROWS) {
            int gr = ms + r; if (gr > IH - 1) gr = IH - 1;
            const int h = gy * IH + gr;
            const float rely = (iy - (float)(h * s + sh)) * inv_soi;

            const float* fbase = fcol + (size_t)h * WW;
            float4 F[8];
            #pragma unroll
            for (int c = 0; c < 8; ++c)
                F[c] = *(const float4*)(fbase + (size_t)c * HW);

            float4 res;
            float* rv = &res.x;
            #pragma unroll
            for (int jp = 0; jp < 4; ++jp) {
                const float relx = relx0 - (float)jp * dstep;
                float f[8];
                #pragma unroll
                for (int c = 0; c < 8; ++c) f[c] = ((const float*)&F[c])[jp];
                rv[jp] = mlp_px(p, f, relx, rely);
            }
            *(float4*)&wsmask[(((size_t)inst * NSL + j) * MROWS + r) * IW + col4] = res;
        }
    }
}

// ---------------- Probe 2: phase 2 only (ws mask -> upsample) --------------
__global__ __launch_bounds__(256, 6) void dmh_p2(
    const float* __restrict__ wsmask, float* __restrict__ out,
    float* __restrict__ dump)
{
    __shared__ float m[MROWS * IW];

    const int bx   = blockIdx.x;
    const int inst = bx / NSL;
    const int j    = bx - inst * NSL;
    const int tid  = threadIdx.x;

    const int orow0 = j * 16;
    const int ms    = (orow0 * 95) / 191;

    // cooperative mask load: 10*128 floats = 320 float4
    {
        const float4* src = (const float4*)(wsmask + ((size_t)inst * NSL + j) * MROWS * IW);
        float4* dst = (float4*)m;
        dst[tid] = src[tid];                 // t = 0..255
        if (tid < 64) dst[256 + tid] = src[256 + tid];
    }
    __syncthreads();

    const int ocol = tid;
    const float wpos = (float)ocol * (127.0f / 255.0f);
    int wlo = (int)wpos; if (wlo > IW - 2) wlo = IW - 2;
    const float fw = wpos - (float)wlo;

    float* obase = (blockIdx.z == 0) ? out : dump;
    float* op = obase + (size_t)inst * HW + (size_t)orow0 * WW + ocol;

    float v00 = m[wlo];
    float v01 = m[wlo + 1];
    float v10 = m[IW + wlo];
    float v11 = m[IW + wlo + 1];
    int cur = 0;
    {
        const float fh = (float)orow0 * (95.0f / 191.0f) - (float)ms;
        const float top = fmaf(fw, v01 - v00, v00);
        const float bot = fmaf(fw, v11 - v10, v10);
        const float val = fmaf(fh, bot - top, top);
        op[0] = 1.0f / (1.0f + __expf(-val));
    }
    #pragma unroll
    for (int r = 1; r < 16; ++r) {
        const int orow = orow0 + r;
        int ihlo = (orow * 95) / 191;
        if (ihlo > IH - 2) ihlo = IH - 2;
        const float fh = (float)orow * (95.0f / 191.0f) - (float)ihlo;
        const int rl = ihlo - ms;
        if (rl != cur) {
            v00 = v10; v01 = v11;
            v10 = m[(rl + 1) * IW + wlo];
            v11 = m[(rl + 1) * IW + wlo + 1];
            cur = rl;
        }
        const float top = fmaf(fw, v01 - v00, v00);
        const float bot = fmaf(fw, v11 - v10, v10);
        const float val = fmaf(fh, bot - top, top);
        op[(size_t)r * WW] = 1.0f / (1.0f + __expf(-val));
    }
}

// ---------------- r9 fused kernel (verbatim) — rewrites d_out --------------
__global__ __launch_bounds__(256, 6) void dmh_kernel(
    const float* __restrict__ mf, const float* __restrict__ params,
    const float* __restrict__ locs, const int* __restrict__ im_inds,
    const int* __restrict__ fpn, const int* __restrict__ stride_p,
    float* __restrict__ out)
{
    __shared__ float m[MROWS * IW];

    const int bx   = blockIdx.x;
    const int inst = bx / NSL;
    const int j    = bx - inst * NSL;
    const int tid  = threadIdx.x;

    const int s  = stride_p[0];
    const int sh = s >> 1;
    float ix, iy, inv_soi; int im, gx, gy;
    inst_setup(locs, im_inds, fpn, inst, ix, iy, inv_soi, im, gx, gy);
    const float* __restrict__ p = params + inst * 169;

    const int orow0 = j * 16;
    const int ms    = (orow0 * 95) / 191;

    {
        const int col4 = (tid & 31) * 4;
        const int rs   = tid >> 5;
        const float relx0 = (ix - (float)((gx * IW + col4) * s + sh)) * inv_soi;
        const float dstep = (float)s * inv_soi;
        const float* fcol = mf + (size_t)(im * 8) * HW + gx * IW + col4;

        #pragma unroll
        for (int pass = 0; pass < 2; ++pass) {
            const int r = rs + pass * 8;
            if (r < MROWS) {
                int gr = ms + r; if (gr > IH - 1) gr = IH - 1;
                const int h = gy * IH + gr;
                const float rely = (iy - (float)(h * s + sh)) * inv_soi;

                const float* fbase = fcol + (size_t)h * WW;
                float4 F[8];
                #pragma unroll
                for (int c = 0; c < 8; ++c)
                    F[c] = *(const float4*)(fbase + (size_t)c * HW);

                float4 res;
                float* rv = &res.x;
                #pragma unroll
                for (int jp = 0; jp < 4; ++jp) {
                    const float relx = relx0 - (float)jp * dstep;
                    float f[8];
                    #pragma unroll
                    for (int c = 0; c < 8; ++c) f[c] = ((const float*)&F[c])[jp];
                    rv[jp] = mlp_px(p, f, relx, rely);
                }
                *(float4*)&m[r * IW + col4] = res;
            }
        }
    }
    __syncthreads();

    {
        const int ocol = tid;
        const float wpos = (float)ocol * (127.0f / 255.0f);
        int wlo = (int)wpos; if (wlo > IW - 2) wlo = IW - 2;
        const float fw = wpos - (float)wlo;

        float* op = out + (size_t)inst * HW + (size_t)orow0 * WW + ocol;

        float v00 = m[wlo];
        float v01 = m[wlo + 1];
        float v10 = m[IW + wlo];
        float v11 = m[IW + wlo + 1];
        int cur = 0;
        {
            const float fh = (float)orow0 * (95.0f / 191.0f) - (float)ms;
            const float top = fmaf(fw, v01 - v00, v00);
            const float bot = fmaf(fw, v11 - v10, v10);
            const float val = fmaf(fh, bot - top, top);
            op[0] = 1.0f / (1.0f + __expf(-val));
        }
        #pragma unroll
        for (int r = 1; r < 16; ++r) {
            const int orow = orow0 + r;
            int ihlo = (orow * 95) / 191;
            if (ihlo > IH - 2) ihlo = IH - 2;
            const float fh = (float)orow * (95.0f / 191.0f) - (float)ihlo;
            const int rl = ihlo - ms;
            if (rl != cur) {
                v00 = v10; v01 = v11;
                v10 = m[(rl + 1) * IW + wlo];
                v11 = m[(rl + 1) * IW + wlo + 1];
                cur = rl;
            }
            const float top = fmaf(fw, v01 - v00, v00);
            const float bot = fmaf(fw, v11 - v10, v10);
            const float val = fmaf(fh, bot - top, top);
            op[(size_t)r * WW] = 1.0f / (1.0f + __expf(-val));
        }
    }
}

extern "C" void kernel_launch(void* const* d_in, const int* in_sizes, int n_in,
                              void* d_out, int out_size, void* d_ws, size_t ws_size,
                              hipStream_t stream) {
    const float* mf       = (const float*)d_in[0];
    const float* params   = (const float*)d_in[1];
    const float* locs     = (const float*)d_in[2];
    const int*   im_inds  = (const int*)d_in[3];
    const int*   fpn      = (const int*)d_in[4];
    const int*   stride_p = (const int*)d_in[5];
    float*       out      = (float*)d_out;

    const size_t need = WS_DUMP_OFF + (size_t)128 * HW * sizeof(float);
    if (ws_size >= need) {
        float* wsmask = (float*)d_ws;
        float* wsdump = (float*)((char*)d_ws + WS_DUMP_OFF);
        dmh_p1<<<dim3(1536, 1, 4),  dim3(256), 0, stream>>>(
            mf, params, locs, im_inds, fpn, stride_p, wsmask);
        dmh_p2<<<dim3(1536, 1, 10), dim3(256), 0, stream>>>(wsmask, out, wsdump);
    }
    dmh_kernel<<<dim3(1536), dim3(256), 0, stream>>>(
        mf, params, locs, im_inds, fpn, stride_p, out);
}